// Round 5
// baseline (976.462 us; speedup 1.0000x reference)
//
#include <hip/hip_runtime.h>
#include <cstdint>
#include <cstddef>

typedef __attribute__((ext_vector_type(8))) short short8;   // 8 bf16 (4 VGPRs)
typedef __attribute__((ext_vector_type(4))) float f32x4;    // 16x16 MFMA acc

#define DEV __device__ __forceinline__

DEV uint32_t cvt_pk_bf16(float lo, float hi){
  uint32_t r;
  asm("v_cvt_pk_bf16_f32 %0, %1, %2" : "=v"(r) : "v"(lo), "v"(hi));
  return r;
}

union FragU { uint32_t u[4]; short8 s; };
DEV short8 frag4(uint32_t a, uint32_t b, uint32_t c, uint32_t d){
  FragU f; f.u[0]=a; f.u[1]=b; f.u[2]=c; f.u[3]=d; return f.s;
}

DEV float fast_exp2(float x){
#if __has_builtin(__builtin_amdgcn_exp2f)
  return __builtin_amdgcn_exp2f(x);
#else
  return exp2f(x);
#endif
}
DEV float fast_rcp(float x){
#if __has_builtin(__builtin_amdgcn_rcpf)
  return __builtin_amdgcn_rcpf(x);
#else
  return 1.0f/x;
#endif
}

// tanh(z) from t = e^(2z): 1 - 2/(t+1). NaN-free (t=inf->1, t=0->-1).
DEV float tanh_from_t(float t){
  return __builtin_fmaf(-2.0f, fast_rcp(t + 1.0f), 1.0f);
}

// 16x16x32 operand map (HW-verified for B via tr_read m156/m162; A symmetric):
// lane group g = lane>>4, elem i -> k = 4g + (i&3) + 16*(i>>2).
DEV int jword(int s, int g, int w){ return 32*s + 4*g + ((2*w)&3) + 16*(w>>1); }

// split f32 pair into bf16 hi-word and bf16 lo-word (compensated)
DEV void hilo(float a, float b, uint32_t& uh, uint32_t& ul){
  uh = cvt_pk_bf16(a, b);
  float ha = __uint_as_float(uh << 16);
  float hb = __uint_as_float(uh & 0xFFFF0000u);
  ul = cvt_pk_bf16(a - ha, b - hb);
}

__global__ __launch_bounds__(256, 3) void ctrnn16(
    const float* __restrict__ gin,  const float* __restrict__ W_in,
    const float* __restrict__ b_in, const float* __restrict__ W_dyn,
    const float* __restrict__ b_dyn,const float* __restrict__ tau,
    const float* __restrict__ W_out,const float* __restrict__ b_out,
    float* __restrict__ gout, int Btot)
{
  const float S = 2.88539008177792681f;   // 2*log2(e): exp2(S*z) = e^(2z)
  const float dt = 0.1f;
  const int lane = (int)(threadIdx.x & 63);
  const int g    = lane >> 4;             // 16-lane group
  const int c    = lane & 15;             // batch col (B/D) and M-row (A)
  const int wid  = (int)((blockIdx.x * blockDim.x + threadIdx.x) >> 6);
  const size_t rb = (size_t)wid * 16 + c; // this lane's batch row

  // ---- persistent per-lane constants (D-form i = 4*mt+e -> h = 16mt+4g+e) ----
  float niT[16], base[16], winc[16];
  #pragma unroll
  for(int mt=0;mt<4;++mt)
    #pragma unroll
    for(int e=0;e<4;++e){
      int h = 16*mt + 4*g + e;
      int i = 4*mt + e;
      niT [i] = -1.0f / tau[h];
      base[i] = b_dyn[h]*S;                          // S*(b + w_t * t), t=0
      winc[i] = W_dyn[(size_t)64*64 + h]*S*(0.5f*dt); // S*w_t*(dt/2)
    }

  // ---- A-fragments for W_dyn^T (pre-scaled by S), kept as raw words ----
  uint32_t Adw[4][2][4];
  #pragma unroll
  for(int mt=0;mt<4;++mt){
    int hc = 16*mt + c;
    #pragma unroll
    for(int s=0;s<2;++s)
      #pragma unroll
      for(int w=0;w<4;++w){
        int j0 = jword(s,g,w);
        Adw[mt][s][w] = cvt_pk_bf16(W_dyn[(size_t)j0*64 + hc]*S,
                                    W_dyn[(size_t)(j0+1)*64 + hc]*S);
      }
  }

  // ---- pin persistent registers: forbid the compiler from re-sinking the
  // builds into the step loop (suspected cause of round-4's hidden reloads) ----
  #pragma unroll
  for(int mt=0;mt<4;++mt)
    #pragma unroll
    for(int s=0;s<2;++s)
      #pragma unroll
      for(int w=0;w<4;++w)
        asm volatile("" : "+v"(Adw[mt][s][w]));
  #pragma unroll
  for(int i=0;i<16;++i){
    asm volatile("" : "+v"(niT[i]));
    asm volatile("" : "+v"(winc[i]));
  }

  // ---------- Phase A: x0 = tanh(inputs @ W_in + b_in), hi/lo inputs ----------
  float xx[16], cur[16], ks[16];
  {
    short8 bhA[4], blA[4];
    #pragma unroll
    for(int s=0;s<4;++s){
      uint32_t uh[4], ul[4];
      #pragma unroll
      for(int w=0;w<4;++w){
        int j0 = jword(s,g,w);
        float2 v = *reinterpret_cast<const float2*>(gin + rb*128 + j0);
        hilo(v.x, v.y, uh[w], ul[w]);
      }
      bhA[s]=frag4(uh[0],uh[1],uh[2],uh[3]);
      blA[s]=frag4(ul[0],ul[1],ul[2],ul[3]);
    }
    #pragma unroll
    for(int mt=0;mt<4;++mt){
      int hc = 16*mt + c;
      f32x4 acc = {0.0f,0.0f,0.0f,0.0f};
      #pragma unroll
      for(int s=0;s<4;++s){
        uint32_t u[4];
        #pragma unroll
        for(int w=0;w<4;++w){
          int j0 = jword(s,g,w);
          u[w] = cvt_pk_bf16(W_in[(size_t)j0*64 + hc]*S,
                             W_in[(size_t)(j0+1)*64 + hc]*S);
        }
        short8 a = frag4(u[0],u[1],u[2],u[3]);
        acc = __builtin_amdgcn_mfma_f32_16x16x32_bf16(a, bhA[s], acc, 0,0,0);
        acc = __builtin_amdgcn_mfma_f32_16x16x32_bf16(a, blA[s], acc, 0,0,0);
      }
      #pragma unroll
      for(int e=0;e<4;++e){
        int h = 16*mt + 4*g + e;
        float z = acc[e] + b_in[h]*S;
        xx[4*mt+e] = tanh_from_t(fast_exp2(z));
      }
    }
  }
  #pragma unroll
  for(int i=0;i<16;++i) cur[i]=xx[i];

  // ---------- RK4 loop: single-bf16 feedback, ks accumulator ----------
  // EVAL(EV, WKS, WCUR): one dyn evaluation; branches on literal EV fold.
  #define EVALX(EV, WKS, WCUR) do {                                          \
    uint32_t ub[8];                                                          \
    _Pragma("unroll")                                                        \
    for(int w=0;w<8;++w) ub[w]=cvt_pk_bf16(cur[2*w],cur[2*w+1]);             \
    short8 B0=frag4(ub[0],ub[1],ub[2],ub[3]);                                \
    short8 B1=frag4(ub[4],ub[5],ub[6],ub[7]);                                \
    _Pragma("unroll")                                                        \
    for(int mt=0;mt<4;++mt){                                                 \
      short8 A0=frag4(Adw[mt][0][0],Adw[mt][0][1],Adw[mt][0][2],Adw[mt][0][3]);\
      short8 A1=frag4(Adw[mt][1][0],Adw[mt][1][1],Adw[mt][1][2],Adw[mt][1][3]);\
      f32x4 acc={0.0f,0.0f,0.0f,0.0f};                                       \
      acc=__builtin_amdgcn_mfma_f32_16x16x32_bf16(A0,B0,acc,0,0,0);          \
      acc=__builtin_amdgcn_mfma_f32_16x16x32_bf16(A1,B1,acc,0,0,0);          \
      _Pragma("unroll")                                                      \
      for(int e=0;e<4;e+=2){                                                 \
        int i=4*mt+e;                                                        \
        float z0=acc[e]  +base[i];                                           \
        float z1=acc[e+1]+base[i+1];                                         \
        float q0=__builtin_fmaf(cur[i],  niT[i],  1.0f);                     \
        float q1=__builtin_fmaf(cur[i+1],niT[i+1],1.0f);                     \
        float t0=fast_exp2(z0), t1=fast_exp2(z1);                            \
        float P0=t0+1.0f, P1=t1+1.0f;                                        \
        float r =fast_rcp(P0*P1);                                            \
        float r0=r*P1, r1=r*P0;                                              \
        float k0=__builtin_fmaf(-2.0f,r0,q0);                                \
        float k1=__builtin_fmaf(-2.0f,r1,q1);                                \
        if (EV==0){ ks[i]=k0; ks[i+1]=k1; }                                  \
        else { ks[i]  =__builtin_fmaf((float)(WKS),k0,ks[i]);                \
               ks[i+1]=__builtin_fmaf((float)(WKS),k1,ks[i+1]); }            \
        if (EV<3){ cur[i]  =__builtin_fmaf((float)(WCUR),k0,xx[i]);          \
                   cur[i+1]=__builtin_fmaf((float)(WCUR),k1,xx[i+1]); }      \
        else { xx[i]  =__builtin_fmaf(dt/6.0f,ks[i],  xx[i]);                \
               xx[i+1]=__builtin_fmaf(dt/6.0f,ks[i+1],xx[i+1]);              \
               cur[i]=xx[i]; cur[i+1]=xx[i+1]; }                             \
      }                                                                      \
    }                                                                        \
  } while(0)

  #pragma unroll 1
  for(int n=0;n<10;++n){
    EVALX(0, 0.0f, 0.05f);
    #pragma unroll
    for(int i=0;i<16;++i) base[i]+=winc[i];
    EVALX(1, 2.0f, 0.05f);
    EVALX(2, 2.0f, 0.10f);
    #pragma unroll
    for(int i=0;i<16;++i) base[i]+=winc[i];
    EVALX(3, 1.0f, 0.0f);
  }
  #undef EVALX

  // ---------- Phase C: out = hidden @ W_out + b_out ----------
  {
    uint32_t u[4];
    #pragma unroll
    for(int w=0;w<4;++w) u[w] = cvt_pk_bf16(xx[2*w], xx[2*w+1]);  // bo[j]=x[j]
    short8 bo = frag4(u[0],u[1],u[2],u[3]);

    float* op = gout + rb*32;
    #pragma unroll
    for(int mt2=0;mt2<2;++mt2){
      int oc = 16*mt2 + c;
      uint32_t a[4];
      #pragma unroll
      for(int w=0;w<4;++w){
        int j0 = jword(0,g,w);
        a[w] = cvt_pk_bf16(W_out[(size_t)j0*32 + oc],
                           W_out[(size_t)(j0+1)*32 + oc]);
      }
      short8 ao = frag4(a[0],a[1],a[2],a[3]);
      f32x4 zc = {0.0f,0.0f,0.0f,0.0f};
      f32x4 acc = __builtin_amdgcn_mfma_f32_16x16x32_bf16(ao, bo, zc, 0,0,0);
      float4 v;
      v.x = acc[0] + b_out[16*mt2 + 4*g + 0];
      v.y = acc[1] + b_out[16*mt2 + 4*g + 1];
      v.z = acc[2] + b_out[16*mt2 + 4*g + 2];
      v.w = acc[3] + b_out[16*mt2 + 4*g + 3];
      *reinterpret_cast<float4*>(op + 16*mt2 + 4*g) = v;
    }
    float* hp = gout + (size_t)Btot*32 + rb*32;
    float4 h0; h0.x=xx[0]; h0.y=xx[1]; h0.z=xx[2]; h0.w=xx[3];
    *reinterpret_cast<float4*>(hp + 4*g) = h0;        // h = 4g+e
    float4 h1; h1.x=xx[4]; h1.y=xx[5]; h1.z=xx[6]; h1.w=xx[7];
    *reinterpret_cast<float4*>(hp + 16 + 4*g) = h1;   // h = 16+4g+e
  }
}

extern "C" void kernel_launch(void* const* d_in, const int* in_sizes, int n_in,
                              void* d_out, int out_size, void* d_ws, size_t ws_size,
                              hipStream_t stream) {
  const float* gin  = (const float*)d_in[0];
  const float* W_in = (const float*)d_in[1];
  const float* b_in = (const float*)d_in[2];
  const float* W_dyn= (const float*)d_in[3];
  const float* b_dyn= (const float*)d_in[4];
  const float* tau  = (const float*)d_in[5];
  const float* W_out= (const float*)d_in[6];
  const float* b_out= (const float*)d_in[7];
  float* gout = (float*)d_out;
  const int Btot = in_sizes[0] / 128;              // 262144
  const int rows_per_block = 64;                   // 4 waves * 16 rows
  const int grid = (Btot + rows_per_block - 1) / rows_per_block;
  hipLaunchKernelGGL(ctrnn16, dim3(grid), dim3(256), 0, stream,
                     gin, W_in, b_in, W_dyn, b_dyn, tau, W_out, b_out, gout, Btot);
}

// Round 7
// 235.876 us; speedup vs baseline: 4.1397x; 4.1397x over previous
//
#include <hip/hip_runtime.h>
#include <cstdint>
#include <cstddef>

typedef __attribute__((ext_vector_type(8))) short short8;   // 8 bf16 (4 VGPRs)
typedef __attribute__((ext_vector_type(4))) float f32x4;    // 16x16 MFMA acc

#define DEV __device__ __forceinline__

DEV uint32_t cvt_pk_bf16(float lo, float hi){
  uint32_t r;
  asm("v_cvt_pk_bf16_f32 %0, %1, %2" : "=v"(r) : "v"(lo), "v"(hi));
  return r;
}

union FragU { uint32_t u[4]; short8 s; };
DEV short8 frag4(uint32_t a, uint32_t b, uint32_t c, uint32_t d){
  FragU f; f.u[0]=a; f.u[1]=b; f.u[2]=c; f.u[3]=d; return f.s;
}

DEV float fast_exp2(float x){
#if __has_builtin(__builtin_amdgcn_exp2f)
  return __builtin_amdgcn_exp2f(x);
#else
  return exp2f(x);
#endif
}
DEV float fast_rcp(float x){
#if __has_builtin(__builtin_amdgcn_rcpf)
  return __builtin_amdgcn_rcpf(x);
#else
  return 1.0f/x;
#endif
}

// tanh(z) from t = e^(2z): 1 - 2/(t+1). NaN-free (t=inf->1, t=0->-1).
DEV float tanh_from_t(float t){
  return __builtin_fmaf(-2.0f, fast_rcp(t + 1.0f), 1.0f);
}

// 16x16x32 operand map (B HW-verified m156/m162; A symmetric — validated by
// round-4/5 passes): lane group g=lane>>4, elem i -> k = 4g + (i&3) + 16*(i>>2).
DEV int jword(int s, int g, int w){ return 32*s + 4*g + ((2*w)&3) + 16*(w>>1); }

// split f32 pair into bf16 hi-word and bf16 lo-word (compensated)
DEV void hilo(float a, float b, uint32_t& uh, uint32_t& ul){
  uh = cvt_pk_bf16(a, b);
  float ha = __uint_as_float(uh << 16);
  float hb = __uint_as_float(uh & 0xFFFF0000u);
  ul = cvt_pk_bf16(a - ha, b - hb);
}

__global__ __launch_bounds__(256, 2) void ctrnn16(
    const float* __restrict__ gin,  const float* __restrict__ W_in,
    const float* __restrict__ b_in, const float* __restrict__ W_dyn,
    const float* __restrict__ b_dyn,const float* __restrict__ tau,
    const float* __restrict__ W_out,const float* __restrict__ b_out,
    float* __restrict__ gout, int Btot)
{
  const float S = 2.88539008177792681f;   // 2*log2(e): exp2(S*z) = e^(2z)
  const float dt = 0.1f;
  const int lane = (int)(threadIdx.x & 63);
  const int g    = lane >> 4;             // 16-lane group
  const int c    = lane & 15;             // batch col (B/D) and M-row (A)
  const int wid  = (int)((blockIdx.x * blockDim.x + threadIdx.x) >> 6);
  const size_t rb = (size_t)wid * 16 + c; // this lane's batch row

  // ---- persistent per-lane constants (D-form i = 4*mt+e -> h = 16mt+4g+e) ----
  float niT[16], base[16], winc[16];
  #pragma unroll
  for(int mt=0;mt<4;++mt)
    #pragma unroll
    for(int e=0;e<4;++e){
      int h = 16*mt + 4*g + e;
      int i = 4*mt + e;
      niT [i] = -1.0f / tau[h];
      base[i] = b_dyn[h]*S;                           // S*(b + w_t*t), t=0
      winc[i] = W_dyn[(size_t)64*64 + h]*S*(0.5f*dt); // S*w_t*(dt/2)
    }

  // ---- A-fragments for W_dyn^T (pre-scaled by S) ----
  uint32_t Adw[4][2][4];
  #pragma unroll
  for(int mt=0;mt<4;++mt){
    int hc = 16*mt + c;
    #pragma unroll
    for(int s=0;s<2;++s)
      #pragma unroll
      for(int w=0;w<4;++w){
        int j0 = jword(s,g,w);
        Adw[mt][s][w] = cvt_pk_bf16(W_dyn[(size_t)j0*64 + hc]*S,
                                    W_dyn[(size_t)(j0+1)*64 + hc]*S);
      }
  }

  // ---------- Phase A: x0 = tanh(inputs @ W_in + b_in), hi/lo inputs ----------
  float xx[16], cur[16], ks[16];
  {
    short8 bhA[4], blA[4];
    #pragma unroll
    for(int s=0;s<4;++s){
      uint32_t uh[4], ul[4];
      #pragma unroll
      for(int w=0;w<4;++w){
        int j0 = jword(s,g,w);
        float2 v = *reinterpret_cast<const float2*>(gin + rb*128 + j0);
        hilo(v.x, v.y, uh[w], ul[w]);
      }
      bhA[s]=frag4(uh[0],uh[1],uh[2],uh[3]);
      blA[s]=frag4(ul[0],ul[1],ul[2],ul[3]);
    }
    #pragma unroll
    for(int mt=0;mt<4;++mt){
      int hc = 16*mt + c;
      f32x4 acc = {0.0f,0.0f,0.0f,0.0f};
      #pragma unroll
      for(int s=0;s<4;++s){
        uint32_t u[4];
        #pragma unroll
        for(int w=0;w<4;++w){
          int j0 = jword(s,g,w);
          u[w] = cvt_pk_bf16(W_in[(size_t)j0*64 + hc]*S,
                             W_in[(size_t)(j0+1)*64 + hc]*S);
        }
        short8 a = frag4(u[0],u[1],u[2],u[3]);
        acc = __builtin_amdgcn_mfma_f32_16x16x32_bf16(a, bhA[s], acc, 0,0,0);
        acc = __builtin_amdgcn_mfma_f32_16x16x32_bf16(a, blA[s], acc, 0,0,0);
      }
      #pragma unroll
      for(int e=0;e<4;++e){
        int h = 16*mt + 4*g + e;
        float z = acc[e] + b_in[h]*S;
        xx[4*mt+e] = tanh_from_t(fast_exp2(z));
      }
    }
  }
  #pragma unroll
  for(int i=0;i<16;++i) cur[i]=xx[i];

  // ---------- RK4 loop: single-bf16 feedback, ks accumulator ----------
  #define EVALX(EV, WKS, WCUR) do {                                          \
    uint32_t ub[8];                                                          \
    _Pragma("unroll")                                                        \
    for(int w=0;w<8;++w) ub[w]=cvt_pk_bf16(cur[2*w],cur[2*w+1]);             \
    short8 B0=frag4(ub[0],ub[1],ub[2],ub[3]);                                \
    short8 B1=frag4(ub[4],ub[5],ub[6],ub[7]);                                \
    _Pragma("unroll")                                                        \
    for(int mt=0;mt<4;++mt){                                                 \
      short8 A0=frag4(Adw[mt][0][0],Adw[mt][0][1],Adw[mt][0][2],Adw[mt][0][3]);\
      short8 A1=frag4(Adw[mt][1][0],Adw[mt][1][1],Adw[mt][1][2],Adw[mt][1][3]);\
      f32x4 acc={0.0f,0.0f,0.0f,0.0f};                                       \
      acc=__builtin_amdgcn_mfma_f32_16x16x32_bf16(A0,B0,acc,0,0,0);          \
      acc=__builtin_amdgcn_mfma_f32_16x16x32_bf16(A1,B1,acc,0,0,0);          \
      _Pragma("unroll")                                                      \
      for(int e=0;e<4;e+=2){                                                 \
        int i=4*mt+e;                                                        \
        float z0=acc[e]  +base[i];                                           \
        float z1=acc[e+1]+base[i+1];                                         \
        float q0=__builtin_fmaf(cur[i],  niT[i],  1.0f);                     \
        float q1=__builtin_fmaf(cur[i+1],niT[i+1],1.0f);                     \
        float t0=fast_exp2(z0), t1=fast_exp2(z1);                            \
        float P0=t0+1.0f, P1=t1+1.0f;                                        \
        float r =fast_rcp(P0*P1);                                            \
        float r0=r*P1, r1=r*P0;                                              \
        float k0=__builtin_fmaf(-2.0f,r0,q0);                                \
        float k1=__builtin_fmaf(-2.0f,r1,q1);                                \
        if ((EV)==0){ ks[i]=k0; ks[i+1]=k1; }                                \
        else { ks[i]  =__builtin_fmaf((float)(WKS),k0,ks[i]);                \
               ks[i+1]=__builtin_fmaf((float)(WKS),k1,ks[i+1]); }            \
        if ((EV)<3){ cur[i]  =__builtin_fmaf((float)(WCUR),k0,xx[i]);        \
                     cur[i+1]=__builtin_fmaf((float)(WCUR),k1,xx[i+1]); }    \
        else { xx[i]  =__builtin_fmaf(dt/6.0f,ks[i],  xx[i]);                \
               xx[i+1]=__builtin_fmaf(dt/6.0f,ks[i+1],xx[i+1]);              \
               cur[i]=xx[i]; cur[i+1]=xx[i+1]; }                             \
      }                                                                      \
    }                                                                        \
  } while(0)

  #pragma unroll 1
  for(int n=0;n<10;++n){
    EVALX(0, 0.0f, 0.05f);
    #pragma unroll
    for(int i=0;i<16;++i) base[i]+=winc[i];
    EVALX(1, 2.0f, 0.05f);
    EVALX(2, 2.0f, 0.10f);
    #pragma unroll
    for(int i=0;i<16;++i) base[i]+=winc[i];
    EVALX(3, 1.0f, 0.0f);
  }
  #undef EVALX

  // ---------- Phase C: out = hidden @ W_out + b_out ----------
  {
    uint32_t u[4];
    #pragma unroll
    for(int w=0;w<4;++w) u[w] = cvt_pk_bf16(xx[2*w], xx[2*w+1]);  // bo[j]=x[j]
    short8 bo = frag4(u[0],u[1],u[2],u[3]);

    float* op = gout + rb*32;
    #pragma unroll
    for(int mt2=0;mt2<2;++mt2){
      int oc = 16*mt2 + c;
      uint32_t a[4];
      #pragma unroll
      for(int w=0;w<4;++w){
        int j0 = jword(0,g,w);
        a[w] = cvt_pk_bf16(W_out[(size_t)j0*32 + oc],
                           W_out[(size_t)(j0+1)*32 + oc]);
      }
      short8 ao = frag4(a[0],a[1],a[2],a[3]);
      f32x4 zc = {0.0f,0.0f,0.0f,0.0f};
      f32x4 acc = __builtin_amdgcn_mfma_f32_16x16x32_bf16(ao, bo, zc, 0,0,0);
      float4 v;
      v.x = acc[0] + b_out[16*mt2 + 4*g + 0];
      v.y = acc[1] + b_out[16*mt2 + 4*g + 1];
      v.z = acc[2] + b_out[16*mt2 + 4*g + 2];
      v.w = acc[3] + b_out[16*mt2 + 4*g + 3];
      *reinterpret_cast<float4*>(op + 16*mt2 + 4*g) = v;
    }
    float* hp = gout + (size_t)Btot*32 + rb*32;
    float4 h0; h0.x=xx[0]; h0.y=xx[1]; h0.z=xx[2]; h0.w=xx[3];
    *reinterpret_cast<float4*>(hp + 4*g) = h0;        // h = 4g+e
    float4 h1; h1.x=xx[4]; h1.y=xx[5]; h1.z=xx[6]; h1.w=xx[7];
    *reinterpret_cast<float4*>(hp + 16 + 4*g) = h1;   // h = 16+4g+e
  }
}

extern "C" void kernel_launch(void* const* d_in, const int* in_sizes, int n_in,
                              void* d_out, int out_size, void* d_ws, size_t ws_size,
                              hipStream_t stream) {
  const float* gin  = (const float*)d_in[0];
  const float* W_in = (const float*)d_in[1];
  const float* b_in = (const float*)d_in[2];
  const float* W_dyn= (const float*)d_in[3];
  const float* b_dyn= (const float*)d_in[4];
  const float* tau  = (const float*)d_in[5];
  const float* W_out= (const float*)d_in[6];
  const float* b_out= (const float*)d_in[7];
  float* gout = (float*)d_out;
  const int Btot = in_sizes[0] / 128;              // 262144
  const int rows_per_block = 64;                   // 4 waves * 16 rows
  const int grid = (Btot + rows_per_block - 1) / rows_per_block;
  hipLaunchKernelGGL(ctrnn16, dim3(grid), dim3(256), 0, stream,
                     gin, W_in, b_in, W_dyn, b_dyn, tau, W_out, b_out, gout, Btot);
}

// Round 9
// 226.790 us; speedup vs baseline: 4.3056x; 1.0401x over previous
//
#include <hip/hip_runtime.h>
#include <cstdint>
#include <cstddef>

typedef __attribute__((ext_vector_type(8))) short short8;   // 8 bf16 (4 VGPRs)
typedef __attribute__((ext_vector_type(4))) float f32x4;    // 16x16 MFMA acc

#define DEV __device__ __forceinline__

DEV uint32_t cvt_pk_bf16(float lo, float hi){
  uint32_t r;
  asm("v_cvt_pk_bf16_f32 %0, %1, %2" : "=v"(r) : "v"(lo), "v"(hi));
  return r;
}

union FragU { uint32_t u[4]; short8 s; };
DEV short8 frag4(uint32_t a, uint32_t b, uint32_t c, uint32_t d){
  FragU f; f.u[0]=a; f.u[1]=b; f.u[2]=c; f.u[3]=d; return f.s;
}

DEV float fast_exp2(float x){
#if __has_builtin(__builtin_amdgcn_exp2f)
  return __builtin_amdgcn_exp2f(x);
#else
  return exp2f(x);
#endif
}
DEV float fast_rcp(float x){
#if __has_builtin(__builtin_amdgcn_rcpf)
  return __builtin_amdgcn_rcpf(x);
#else
  return 1.0f/x;
#endif
}

// tanh(z) from t = e^(2z): 1 - 2/(t+1). NaN-free (t=inf->1, t=0->-1).
DEV float tanh_from_t(float t){
  return __builtin_fmaf(-2.0f, fast_rcp(t + 1.0f), 1.0f);
}

// 16x16x32 operand map (B HW-verified m156/m162; A symmetric — validated by
// round-4/5/7 passes): lane group g=lane>>4, elem i -> k = 4g + (i&3) + 16*(i>>2).
DEV int jword(int s, int g, int w){ return 32*s + 4*g + ((2*w)&3) + 16*(w>>1); }

// split f32 pair into bf16 hi-word and bf16 lo-word (compensated)
DEV void hilo(float a, float b, uint32_t& uh, uint32_t& ul){
  uh = cvt_pk_bf16(a, b);
  float ha = __uint_as_float(uh << 16);
  float hb = __uint_as_float(uh & 0xFFFF0000u);
  ul = cvt_pk_bf16(a - ha, b - hb);
}

static __constant__ const float kS = 2.88539008177792681f;  // 2*log2(e)

// ---- setup: precompute the 32 scaled W_dyn^T fragment words per lane ----
// ws[(mt*2+s)*256 + 4*lane + w] — byte-identical values to round 7's Adw.
__global__ void ctrnn_prep(const float* __restrict__ W_dyn,
                           uint32_t* __restrict__ ws){
  const int lane = (int)(threadIdx.x & 63);
  const int g = lane >> 4, c = lane & 15;
  #pragma unroll
  for(int mt=0;mt<4;++mt){
    int hc = 16*mt + c;
    #pragma unroll
    for(int s=0;s<2;++s)
      #pragma unroll
      for(int w=0;w<4;++w){
        int j0 = jword(s,g,w);
        ws[(mt*2+s)*256 + 4*lane + w] =
            cvt_pk_bf16(W_dyn[(size_t)j0*64 + hc]*kS,
                        W_dyn[(size_t)(j0+1)*64 + hc]*kS);
      }
  }
}

__global__ __launch_bounds__(256, 2) void ctrnn16(
    const float* __restrict__ gin,  const float* __restrict__ W_in,
    const float* __restrict__ b_in, const float* __restrict__ W_dyn,
    const float* __restrict__ b_dyn,const float* __restrict__ tau,
    const float* __restrict__ W_out,const float* __restrict__ b_out,
    const uint32_t* __restrict__ wsA,
    float* __restrict__ gout, int Btot)
{
  const float S = 2.88539008177792681f;   // 2*log2(e): exp2(S*z) = e^(2z)
  const float dt = 0.1f;
  const int lane = (int)(threadIdx.x & 63);
  const int g    = lane >> 4;             // 16-lane group
  const int c    = lane & 15;             // batch col (B/D) and M-row (A)
  const int wid  = (int)((blockIdx.x * blockDim.x + threadIdx.x) >> 6);
  const size_t rb = (size_t)wid * 16 + c; // this lane's batch row

  // ---- persistent per-lane constants (D-form i = 4*mt+e -> h = 16mt+4g+e) ----
  float niT[16], base[16], winc[16];
  #pragma unroll
  for(int mt=0;mt<4;++mt)
    #pragma unroll
    for(int e=0;e<4;++e){
      int h = 16*mt + 4*g + e;
      int i = 4*mt + e;
      niT [i] = -1.0f / tau[h];
      base[i] = b_dyn[h]*S;                           // S*(b + w_t*t), t=0
      winc[i] = W_dyn[(size_t)64*64 + h]*S*(0.5f*dt); // S*w_t*(dt/2)
    }

  // ---------- Phase A: x0 = tanh(inputs @ W_in + b_in), hi/lo inputs ----------
  float xx[16], cur[16], ks[16];
  {
    short8 bhA[4], blA[4];
    #pragma unroll
    for(int s=0;s<4;++s){
      uint32_t uh[4], ul[4];
      #pragma unroll
      for(int w=0;w<4;++w){
        int j0 = jword(s,g,w);
        float2 v = *reinterpret_cast<const float2*>(gin + rb*128 + j0);
        hilo(v.x, v.y, uh[w], ul[w]);
      }
      bhA[s]=frag4(uh[0],uh[1],uh[2],uh[3]);
      blA[s]=frag4(ul[0],ul[1],ul[2],ul[3]);
    }
    #pragma unroll
    for(int mt=0;mt<4;++mt){
      int hc = 16*mt + c;
      f32x4 acc = {0.0f,0.0f,0.0f,0.0f};
      #pragma unroll
      for(int s=0;s<4;++s){
        uint32_t u[4];
        #pragma unroll
        for(int w=0;w<4;++w){
          int j0 = jword(s,g,w);
          u[w] = cvt_pk_bf16(W_in[(size_t)j0*64 + hc]*S,
                             W_in[(size_t)(j0+1)*64 + hc]*S);
        }
        short8 a = frag4(u[0],u[1],u[2],u[3]);
        acc = __builtin_amdgcn_mfma_f32_16x16x32_bf16(a, bhA[s], acc, 0,0,0);
        acc = __builtin_amdgcn_mfma_f32_16x16x32_bf16(a, blA[s], acc, 0,0,0);
      }
      #pragma unroll
      for(int e=0;e<4;++e){
        int h = 16*mt + 4*g + e;
        float z = acc[e] + b_in[h]*S;
        xx[4*mt+e] = tanh_from_t(fast_exp2(z));
      }
    }
  }
  #pragma unroll
  for(int i=0;i<16;++i) cur[i]=xx[i];

  // per-lane base pointer into the prepared fragment table
  const uint32_t* wf = wsA + 4*lane;

  // ---------- RK4 loop: A-frags via coalesced global loads, base C-init ----------
  #define EVALX(EV, WKS, WCUR) do {                                          \
    uint32_t ub[8];                                                          \
    _Pragma("unroll")                                                        \
    for(int w=0;w<8;++w) ub[w]=cvt_pk_bf16(cur[2*w],cur[2*w+1]);             \
    short8 B0=frag4(ub[0],ub[1],ub[2],ub[3]);                                \
    short8 B1=frag4(ub[4],ub[5],ub[6],ub[7]);                                \
    _Pragma("unroll")                                                        \
    for(int mt=0;mt<4;++mt){                                                 \
      const short8 A0 = *reinterpret_cast<const short8*>(wf + (mt*2+0)*256); \
      const short8 A1 = *reinterpret_cast<const short8*>(wf + (mt*2+1)*256); \
      f32x4 acc={base[4*mt],base[4*mt+1],base[4*mt+2],base[4*mt+3]};         \
      acc=__builtin_amdgcn_mfma_f32_16x16x32_bf16(A0,B0,acc,0,0,0);          \
      acc=__builtin_amdgcn_mfma_f32_16x16x32_bf16(A1,B1,acc,0,0,0);          \
      _Pragma("unroll")                                                      \
      for(int e=0;e<4;e+=2){                                                 \
        int i=4*mt+e;                                                        \
        float q0=__builtin_fmaf(cur[i],  niT[i],  1.0f);                     \
        float q1=__builtin_fmaf(cur[i+1],niT[i+1],1.0f);                     \
        float t0=fast_exp2(acc[e]), t1=fast_exp2(acc[e+1]);                  \
        float P0=t0+1.0f, P1=t1+1.0f;                                        \
        float r =fast_rcp(P0*P1);                                            \
        float r0=r*P1, r1=r*P0;                                              \
        float k0=__builtin_fmaf(-2.0f,r0,q0);                                \
        float k1=__builtin_fmaf(-2.0f,r1,q1);                                \
        if ((EV)==0){ ks[i]=k0; ks[i+1]=k1; }                                \
        else { ks[i]  =__builtin_fmaf((float)(WKS),k0,ks[i]);                \
               ks[i+1]=__builtin_fmaf((float)(WKS),k1,ks[i+1]); }            \
        if ((EV)<3){ cur[i]  =__builtin_fmaf((float)(WCUR),k0,xx[i]);        \
                     cur[i+1]=__builtin_fmaf((float)(WCUR),k1,xx[i+1]); }    \
        else { xx[i]  =__builtin_fmaf(dt/6.0f,ks[i],  xx[i]);                \
               xx[i+1]=__builtin_fmaf(dt/6.0f,ks[i+1],xx[i+1]);              \
               cur[i]=xx[i]; cur[i+1]=xx[i+1]; }                             \
      }                                                                      \
    }                                                                        \
  } while(0)

  #pragma unroll 1
  for(int n=0;n<10;++n){
    EVALX(0, 0.0f, 0.05f);
    #pragma unroll
    for(int i=0;i<16;++i) base[i]+=winc[i];
    EVALX(1, 2.0f, 0.05f);
    EVALX(2, 2.0f, 0.10f);
    #pragma unroll
    for(int i=0;i<16;++i) base[i]+=winc[i];
    EVALX(3, 1.0f, 0.0f);
  }
  #undef EVALX

  // ---------- Phase C: out = hidden @ W_out + b_out ----------
  {
    uint32_t u[4];
    #pragma unroll
    for(int w=0;w<4;++w) u[w] = cvt_pk_bf16(xx[2*w], xx[2*w+1]);  // bo[j]=x[j]
    short8 bo = frag4(u[0],u[1],u[2],u[3]);

    float* op = gout + rb*32;
    #pragma unroll
    for(int mt2=0;mt2<2;++mt2){
      int oc = 16*mt2 + c;
      uint32_t a[4];
      #pragma unroll
      for(int w=0;w<4;++w){
        int j0 = jword(0,g,w);
        a[w] = cvt_pk_bf16(W_out[(size_t)j0*32 + oc],
                           W_out[(size_t)(j0+1)*32 + oc]);
      }
      short8 ao = frag4(a[0],a[1],a[2],a[3]);
      f32x4 zc = {0.0f,0.0f,0.0f,0.0f};
      f32x4 acc = __builtin_amdgcn_mfma_f32_16x16x32_bf16(ao, bo, zc, 0,0,0);
      float4 v;
      v.x = acc[0] + b_out[16*mt2 + 4*g + 0];
      v.y = acc[1] + b_out[16*mt2 + 4*g + 1];
      v.z = acc[2] + b_out[16*mt2 + 4*g + 2];
      v.w = acc[3] + b_out[16*mt2 + 4*g + 3];
      *reinterpret_cast<float4*>(op + 16*mt2 + 4*g) = v;
    }
    float* hp = gout + (size_t)Btot*32 + rb*32;
    float4 h0; h0.x=xx[0]; h0.y=xx[1]; h0.z=xx[2]; h0.w=xx[3];
    *reinterpret_cast<float4*>(hp + 4*g) = h0;        // h = 4g+e
    float4 h1; h1.x=xx[4]; h1.y=xx[5]; h1.z=xx[6]; h1.w=xx[7];
    *reinterpret_cast<float4*>(hp + 16 + 4*g) = h1;   // h = 16+4g+e
  }
}

extern "C" void kernel_launch(void* const* d_in, const int* in_sizes, int n_in,
                              void* d_out, int out_size, void* d_ws, size_t ws_size,
                              hipStream_t stream) {
  const float* gin  = (const float*)d_in[0];
  const float* W_in = (const float*)d_in[1];
  const float* b_in = (const float*)d_in[2];
  const float* W_dyn= (const float*)d_in[3];
  const float* b_dyn= (const float*)d_in[4];
  const float* tau  = (const float*)d_in[5];
  const float* W_out= (const float*)d_in[6];
  const float* b_out= (const float*)d_in[7];
  float* gout = (float*)d_out;
  uint32_t* ws = (uint32_t*)d_ws;                  // needs 8 KB
  const int Btot = in_sizes[0] / 128;              // 262144
  const int rows_per_block = 64;                   // 4 waves * 16 rows
  const int grid = (Btot + rows_per_block - 1) / rows_per_block;
  hipLaunchKernelGGL(ctrnn_prep, dim3(1), dim3(64), 0, stream, W_dyn, ws);
  hipLaunchKernelGGL(ctrnn16, dim3(grid), dim3(256), 0, stream,
                     gin, W_in, b_in, W_dyn, b_dyn, tau, W_out, b_out,
                     (const uint32_t*)ws, gout, Btot);
}

// Round 13
// 226.641 us; speedup vs baseline: 4.3084x; 1.0007x over previous
//
#include <hip/hip_runtime.h>
#include <cstdint>
#include <cstddef>

typedef __attribute__((ext_vector_type(8))) short short8;   // 8 bf16 (4 VGPRs)
typedef __attribute__((ext_vector_type(4))) float f32x4;    // 16x16 MFMA acc

#define DEV __device__ __forceinline__

DEV uint32_t cvt_pk_bf16(float lo, float hi){
  uint32_t r;
  asm("v_cvt_pk_bf16_f32 %0, %1, %2" : "=v"(r) : "v"(lo), "v"(hi));
  return r;
}

union FragU { uint32_t u[4]; short8 s; };
DEV short8 frag4(uint32_t a, uint32_t b, uint32_t c, uint32_t d){
  FragU f; f.u[0]=a; f.u[1]=b; f.u[2]=c; f.u[3]=d; return f.s;
}

DEV float fast_exp2(float x){
#if __has_builtin(__builtin_amdgcn_exp2f)
  return __builtin_amdgcn_exp2f(x);
#else
  return exp2f(x);
#endif
}
DEV float fast_rcp(float x){
#if __has_builtin(__builtin_amdgcn_rcpf)
  return __builtin_amdgcn_rcpf(x);
#else
  return 1.0f/x;
#endif
}

// tanh(z) from t = e^(2z): 1 - 2/(t+1). NaN-free (t=inf->1, t=0->-1).
DEV float tanh_from_t(float t){
  return __builtin_fmaf(-2.0f, fast_rcp(t + 1.0f), 1.0f);
}

// 16x16x32 operand map (B HW-verified m156/m162; A symmetric — validated by
// round-4/5/7/9 passes): lane group g=lane>>4, elem i -> k = 4g + (i&3) + 16*(i>>2).
DEV int jword(int s, int g, int w){ return 32*s + 4*g + ((2*w)&3) + 16*(w>>1); }

// split f32 pair into bf16 hi-word and bf16 lo-word (compensated)
DEV void hilo(float a, float b, uint32_t& uh, uint32_t& ul){
  uh = cvt_pk_bf16(a, b);
  float ha = __uint_as_float(uh << 16);
  float hb = __uint_as_float(uh & 0xFFFF0000u);
  ul = cvt_pk_bf16(a - ha, b - hb);
}

static __constant__ const float kS = 2.88539008177792681f;  // 2*log2(e)

// ---- setup: precompute the 32 scaled W_dyn^T fragment words per lane ----
// ws[(mt*2+s)*256 + 4*lane + w] — byte-identical values to round 7's Adw.
__global__ void ctrnn_prep(const float* __restrict__ W_dyn,
                           uint32_t* __restrict__ ws){
  const int lane = (int)(threadIdx.x & 63);
  const int g = lane >> 4, c = lane & 15;
  #pragma unroll
  for(int mt=0;mt<4;++mt){
    int hc = 16*mt + c;
    #pragma unroll
    for(int s=0;s<2;++s)
      #pragma unroll
      for(int w=0;w<4;++w){
        int j0 = jword(s,g,w);
        ws[(mt*2+s)*256 + 4*lane + w] =
            cvt_pk_bf16(W_dyn[(size_t)j0*64 + hc]*kS,
                        W_dyn[(size_t)(j0+1)*64 + hc]*kS);
      }
  }
}

__global__ __launch_bounds__(256, 2) void ctrnn16(
    const float* __restrict__ gin,  const float* __restrict__ W_in,
    const float* __restrict__ b_in, const float* __restrict__ W_dyn,
    const float* __restrict__ b_dyn,const float* __restrict__ tau,
    const float* __restrict__ W_out,const float* __restrict__ b_out,
    const uint32_t* __restrict__ wsA,
    float* __restrict__ gout, int Btot)
{
  const float S = 2.88539008177792681f;   // 2*log2(e): exp2(S*z) = e^(2z)
  const float dt = 0.1f;
  const int lane = (int)(threadIdx.x & 63);
  const int g    = lane >> 4;             // 16-lane group
  const int c    = lane & 15;             // batch col (B/D) and M-row (A)
  const int wid  = (int)((blockIdx.x * blockDim.x + threadIdx.x) >> 6);
  const size_t rb = (size_t)wid * 16 + c; // this lane's batch row

  // ---- persistent per-lane constants (D-form i = 4*mt+e -> h = 16mt+4g+e) ----
  float niT[16], base[16], winc[16];
  #pragma unroll
  for(int mt=0;mt<4;++mt)
    #pragma unroll
    for(int e=0;e<4;++e){
      int h = 16*mt + 4*g + e;
      int i = 4*mt + e;
      niT [i] = -1.0f / tau[h];
      base[i] = b_dyn[h]*S;                           // S*(b + w_t*t), t=0
      winc[i] = W_dyn[(size_t)64*64 + h]*S*(0.5f*dt); // S*w_t*(dt/2)
    }

  // ---------- Phase A: x0 = tanh(inputs @ W_in + b_in), hi/lo inputs ----------
  float xx[16], cur[16], ks[16];
  {
    short8 bhA[4], blA[4];
    #pragma unroll
    for(int s=0;s<4;++s){
      uint32_t uh[4], ul[4];
      #pragma unroll
      for(int w=0;w<4;++w){
        int j0 = jword(s,g,w);
        float2 v = *reinterpret_cast<const float2*>(gin + rb*128 + j0);
        hilo(v.x, v.y, uh[w], ul[w]);
      }
      bhA[s]=frag4(uh[0],uh[1],uh[2],uh[3]);
      blA[s]=frag4(ul[0],ul[1],ul[2],ul[3]);
    }
    #pragma unroll
    for(int mt=0;mt<4;++mt){
      int hc = 16*mt + c;
      f32x4 acc = {0.0f,0.0f,0.0f,0.0f};
      #pragma unroll
      for(int s=0;s<4;++s){
        uint32_t u[4];
        #pragma unroll
        for(int w=0;w<4;++w){
          int j0 = jword(s,g,w);
          u[w] = cvt_pk_bf16(W_in[(size_t)j0*64 + hc]*S,
                             W_in[(size_t)(j0+1)*64 + hc]*S);
        }
        short8 a = frag4(u[0],u[1],u[2],u[3]);
        acc = __builtin_amdgcn_mfma_f32_16x16x32_bf16(a, bhA[s], acc, 0,0,0);
        acc = __builtin_amdgcn_mfma_f32_16x16x32_bf16(a, blA[s], acc, 0,0,0);
      }
      #pragma unroll
      for(int e=0;e<4;++e){
        int h = 16*mt + 4*g + e;
        float z = acc[e] + b_in[h]*S;
        xx[4*mt+e] = tanh_from_t(fast_exp2(z));
      }
    }
  }
  #pragma unroll
  for(int i=0;i<16;++i) cur[i]=xx[i];

  // per-lane base pointer into the prepared fragment table
  const uint32_t* wf = wsA + 4*lane;

  // ---------- RK4 loop: A-frags via coalesced global loads, base C-init ----------
  #define EVALX(EV, WKS, WCUR) do {                                          \
    uint32_t ub[8];                                                          \
    _Pragma("unroll")                                                        \
    for(int w=0;w<8;++w) ub[w]=cvt_pk_bf16(cur[2*w],cur[2*w+1]);             \
    short8 B0=frag4(ub[0],ub[1],ub[2],ub[3]);                                \
    short8 B1=frag4(ub[4],ub[5],ub[6],ub[7]);                                \
    _Pragma("unroll")                                                        \
    for(int mt=0;mt<4;++mt){                                                 \
      const short8 A0 = *reinterpret_cast<const short8*>(wf + (mt*2+0)*256); \
      const short8 A1 = *reinterpret_cast<const short8*>(wf + (mt*2+1)*256); \
      f32x4 acc={base[4*mt],base[4*mt+1],base[4*mt+2],base[4*mt+3]};         \
      acc=__builtin_amdgcn_mfma_f32_16x16x32_bf16(A0,B0,acc,0,0,0);          \
      acc=__builtin_amdgcn_mfma_f32_16x16x32_bf16(A1,B1,acc,0,0,0);          \
      _Pragma("unroll")                                                      \
      for(int e=0;e<4;e+=2){                                                 \
        int i=4*mt+e;                                                        \
        float q0=__builtin_fmaf(cur[i],  niT[i],  1.0f);                     \
        float q1=__builtin_fmaf(cur[i+1],niT[i+1],1.0f);                     \
        float t0=fast_exp2(acc[e]), t1=fast_exp2(acc[e+1]);                  \
        float P0=t0+1.0f, P1=t1+1.0f;                                        \
        float r =fast_rcp(P0*P1);                                            \
        float r0=r*P1, r1=r*P0;                                              \
        float k0=__builtin_fmaf(-2.0f,r0,q0);                                \
        float k1=__builtin_fmaf(-2.0f,r1,q1);                                \
        if ((EV)==0){ ks[i]=k0; ks[i+1]=k1; }                                \
        else { ks[i]  =__builtin_fmaf((float)(WKS),k0,ks[i]);                \
               ks[i+1]=__builtin_fmaf((float)(WKS),k1,ks[i+1]); }            \
        if ((EV)<3){ cur[i]  =__builtin_fmaf((float)(WCUR),k0,xx[i]);        \
                     cur[i+1]=__builtin_fmaf((float)(WCUR),k1,xx[i+1]); }    \
        else { xx[i]  =__builtin_fmaf(dt/6.0f,ks[i],  xx[i]);                \
               xx[i+1]=__builtin_fmaf(dt/6.0f,ks[i+1],xx[i+1]);              \
               cur[i]=xx[i]; cur[i+1]=xx[i+1]; }                             \
      }                                                                      \
    }                                                                        \
  } while(0)

  #pragma unroll 1
  for(int n=0;n<10;++n){
    EVALX(0, 0.0f, 0.05f);
    #pragma unroll
    for(int i=0;i<16;++i) base[i]+=winc[i];
    EVALX(1, 2.0f, 0.05f);
    EVALX(2, 2.0f, 0.10f);
    #pragma unroll
    for(int i=0;i<16;++i) base[i]+=winc[i];
    EVALX(3, 1.0f, 0.0f);
  }
  #undef EVALX

  // ---------- Phase C: out = hidden @ W_out + b_out ----------
  {
    uint32_t u[4];
    #pragma unroll
    for(int w=0;w<4;++w) u[w] = cvt_pk_bf16(xx[2*w], xx[2*w+1]);  // bo[j]=x[j]
    short8 bo = frag4(u[0],u[1],u[2],u[3]);

    float* op = gout + rb*32;
    #pragma unroll
    for(int mt2=0;mt2<2;++mt2){
      int oc = 16*mt2 + c;
      uint32_t a[4];
      #pragma unroll
      for(int w=0;w<4;++w){
        int j0 = jword(0,g,w);
        a[w] = cvt_pk_bf16(W_out[(size_t)j0*32 + oc],
                           W_out[(size_t)(j0+1)*32 + oc]);
      }
      short8 ao = frag4(a[0],a[1],a[2],a[3]);
      f32x4 zc = {0.0f,0.0f,0.0f,0.0f};
      f32x4 acc = __builtin_amdgcn_mfma_f32_16x16x32_bf16(ao, bo, zc, 0,0,0);
      float4 v;
      v.x = acc[0] + b_out[16*mt2 + 4*g + 0];
      v.y = acc[1] + b_out[16*mt2 + 4*g + 1];
      v.z = acc[2] + b_out[16*mt2 + 4*g + 2];
      v.w = acc[3] + b_out[16*mt2 + 4*g + 3];
      *reinterpret_cast<float4*>(op + 16*mt2 + 4*g) = v;
    }
    float* hp = gout + (size_t)Btot*32 + rb*32;
    float4 h0; h0.x=xx[0]; h0.y=xx[1]; h0.z=xx[2]; h0.w=xx[3];
    *reinterpret_cast<float4*>(hp + 4*g) = h0;        // h = 4g+e
    float4 h1; h1.x=xx[4]; h1.y=xx[5]; h1.z=xx[6]; h1.w=xx[7];
    *reinterpret_cast<float4*>(hp + 16 + 4*g) = h1;   // h = 16+4g+e
  }
}

extern "C" void kernel_launch(void* const* d_in, const int* in_sizes, int n_in,
                              void* d_out, int out_size, void* d_ws, size_t ws_size,
                              hipStream_t stream) {
  const float* gin  = (const float*)d_in[0];
  const float* W_in = (const float*)d_in[1];
  const float* b_in = (const float*)d_in[2];
  const float* W_dyn= (const float*)d_in[3];
  const float* b_dyn= (const float*)d_in[4];
  const float* tau  = (const float*)d_in[5];
  const float* W_out= (const float*)d_in[6];
  const float* b_out= (const float*)d_in[7];
  float* gout = (float*)d_out;
  uint32_t* ws = (uint32_t*)d_ws;                  // needs 8 KB
  const int Btot = in_sizes[0] / 128;              // 262144
  const int rows_per_block = 64;                   // 4 waves * 16 rows
  const int grid = (Btot + rows_per_block - 1) / rows_per_block;
  hipLaunchKernelGGL(ctrnn_prep, dim3(1), dim3(64), 0, stream, W_dyn, ws);
  hipLaunchKernelGGL(ctrnn16, dim3(grid), dim3(256), 0, stream,
                     gin, W_in, b_in, W_dyn, b_dyn, tau, W_out, b_out,
                     (const uint32_t*)ws, gout, Btot);
}